// Round 1
// baseline (450.288 us; speedup 1.0000x reference)
//
#include <hip/hip_runtime.h>
#include <cstddef>

#define T_DIM 2048
#define B_DIM 64
#define V_DIM 128
#define INV_LN2 1.44269504088896340736f
#define LN2F    0.69314718055994530942f
#define NEG2   -1.442695e30f   // -1e30 (natural log domain) converted to log2 domain

__device__ __forceinline__ float exp2_fast(float x){ return __builtin_amdgcn_exp2f(x); }
__device__ __forceinline__ float log2_fast(float x){ return __builtin_amdgcn_logf(x); }

// logaddexp in log2 domain, 2-way and 3-way
__device__ __forceinline__ float lae2(float a, float b){
  float m = fmaxf(a, b);
  return m + log2_fast(exp2_fast(a - m) + exp2_fast(b - m));
}
__device__ __forceinline__ float lae3(float a, float b, float c){
  float m = fmaxf(fmaxf(a, b), c);
  return m + log2_fast(exp2_fast(a - m) + exp2_fast(b - m) + exp2_fast(c - m));
}

// ---------------- Kernel 1: per-(t,b) log-sum-exp denominator (log2 domain) ----
__global__ __launch_bounds__(256) void lse_kernel(const float* __restrict__ acts,
                                                  float* __restrict__ denom){
  int row  = (blockIdx.x * 256 + threadIdx.x) >> 6;   // one wave per (t,b) row
  int lane = threadIdx.x & 63;
  if (row >= T_DIM * B_DIM) return;
  const float2* r2 = (const float2*)(acts + (size_t)row * V_DIM);
  float2 v = r2[lane];                                 // 2 of 128 values per lane
  float m = fmaxf(v.x, v.y);
  #pragma unroll
  for (int o = 32; o; o >>= 1) m = fmaxf(m, __shfl_xor(m, o, 64));
  float s = exp2_fast((v.x - m) * INV_LN2) + exp2_fast((v.y - m) * INV_LN2);
  #pragma unroll
  for (int o = 32; o; o >>= 1) s += __shfl_xor(s, o, 64);
  if (lane == 0) denom[row] = fmaf(m, INV_LN2, log2_fast(s));  // lse / ln2
}

// ---------------- Kernel 2: per-batch CTC alpha recursion (1 wave / batch) ----
__global__ __launch_bounds__(64) void ctc_kernel(
    const float* __restrict__ acts, const int* __restrict__ labels,
    const int* __restrict__ act_lens, const int* __restrict__ label_lens,
    const float* __restrict__ denom, float* __restrict__ costs)
{
  const int b   = blockIdx.x;
  const int tid = threadIdx.x;                // 0..63, owns states 4t..4t+3 (+256 on t=63)
  const int L   = label_lens[b];
  int alen = act_lens[b];
  if (alen > T_DIM) alen = T_DIM;

  // label offset for this b: sum of label_lens[i<b] via wave butterfly
  int masked = (tid < b) ? label_lens[tid] : 0;
  int off = masked;
  #pragma unroll
  for (int o = 1; o < 64; o <<= 1) off += __shfl_xor(off, o, 64);

  // this thread's two labels (odd lattice states 4t+1 -> j=2t, 4t+3 -> j=2t+1)
  const int j0 = 2 * tid, j1 = 2 * tid + 1, jm1 = 2 * tid - 1;
  const int lab0  = (j0 < L) ? labels[off + j0] : 0;
  const int lab1  = (j1 < L) ? labels[off + j1] : 0;
  const int labm1 = (tid == 0) ? -1 : ((jm1 < L) ? labels[off + jm1] : 0);
  const bool skip1 = (lab0 != 0) && (lab0 != labm1);
  const bool skip3 = (lab1 != 0) && (lab1 != lab0);

  // alpha_{-1}: s=0 -> 0, else NEG (log2 domain)
  float a0 = (tid == 0) ? 0.0f : NEG2;
  float a1 = NEG2, a2 = NEG2, a3 = NEG2, a4 = NEG2;

  const float* actsB = acts + (size_t)b * V_DIM;

  float cxb[8], cx0[8], cx1[8], cdn[8];
  float nxb[8], nx0[8], nx1[8], ndn[8];

  auto prefetch = [&](int tg, float* xb, float* x0, float* x1, float* dn){
    #pragma unroll
    for (int k = 0; k < 8; ++k){
      int t = tg + k; if (t > T_DIM - 1) t = T_DIM - 1;   // clamp; tail unused
      const float* base = actsB + (size_t)t * (B_DIM * V_DIM);
      xb[k] = base[0];        // blank logit (same addr across lanes -> broadcast)
      x0[k] = base[lab0];     // this thread's labels: fixed addresses, affine in t
      x1[k] = base[lab1];
      dn[k] = denom[t * B_DIM + b];
    }
  };

  prefetch(0, cxb, cx0, cx1, cdn);

  for (int t0 = 0; t0 < alen; t0 += 8){
    prefetch(t0 + 8, nxb, nx0, nx1, ndn);   // software pipeline, depth 8
    #pragma unroll
    for (int k = 0; k < 8; ++k){
      int t = t0 + k;
      if (t < alen){                        // wave-uniform branch
        float d  = cdn[k];
        float eb = fmaf(cxb[k], INV_LN2, -d);   // log2 p(blank)
        float e0 = fmaf(cx0[k], INV_LN2, -d);   // log2 p(lab0)
        float e1 = fmaf(cx1[k], INV_LN2, -d);   // log2 p(lab1)
        float Lm1 = __shfl_up(a3, 1, 64);       // alpha[4tid-1] from left neighbor
        if (tid == 0) Lm1 = NEG2;
        float c1 = skip1 ? Lm1 : NEG2;          // alpha[s-2] for s=4t+1
        float c3 = skip3 ? a1  : NEG2;          // alpha[s-2] for s=4t+3
        float n0 = eb + lae2(a0, Lm1);          // s=4t   (blank, no skip)
        float n1 = e0 + lae3(a1, a0, c1);       // s=4t+1 (label)
        float n2 = eb + lae2(a2, a1);           // s=4t+2 (blank)
        float n3 = e1 + lae3(a3, a2, c3);       // s=4t+3 (label)
        float n4 = eb + lae2(a4, a3);           // s=256 on tid 63 (garbage elsewhere, unused)
        a0 = n0; a1 = n1; a2 = n2; a3 = n3; a4 = n4;
      }
    }
    #pragma unroll
    for (int k = 0; k < 8; ++k){ cxb[k]=nxb[k]; cx0[k]=nx0[k]; cx1[k]=nx1[k]; cdn[k]=ndn[k]; }
  }

  // gather final alpha, cost = -ln2 * lae2(alpha[2L], alpha[2L-1])
  __shared__ float A[260];
  A[4*tid+0] = a0; A[4*tid+1] = a1; A[4*tid+2] = a2; A[4*tid+3] = a3;
  if (tid == 63) A[256] = a4;
  __syncthreads();
  if (tid == 0){
    int sL = 2 * L;
    costs[b] = -LN2F * lae2(A[sL], A[sL - 1]);
  }
}

// ---------------- Kernel 3: deterministic sum of per-b costs ------------------
__global__ __launch_bounds__(64) void sum_kernel(const float* __restrict__ costs,
                                                 float* __restrict__ out){
  float v = costs[threadIdx.x];
  #pragma unroll
  for (int o = 32; o; o >>= 1) v += __shfl_xor(v, o, 64);
  if (threadIdx.x == 0) out[0] = v;
}

extern "C" void kernel_launch(void* const* d_in, const int* in_sizes, int n_in,
                              void* d_out, int out_size, void* d_ws, size_t ws_size,
                              hipStream_t stream){
  const float* acts       = (const float*)d_in[0];
  const int*   labels     = (const int*)d_in[1];
  const int*   act_lens   = (const int*)d_in[2];
  const int*   label_lens = (const int*)d_in[3];
  float* denom = (float*)d_ws;                    // T*B floats = 512 KB
  float* costs = denom + (size_t)T_DIM * B_DIM;   // 64 floats
  float* out   = (float*)d_out;

  lse_kernel<<<(T_DIM * B_DIM) / 4, 256, 0, stream>>>(acts, denom);
  ctc_kernel<<<B_DIM, 64, 0, stream>>>(acts, labels, act_lens, label_lens, denom, costs);
  sum_kernel<<<1, 64, 0, stream>>>(costs, out);
}